// Round 1
// baseline (1168.048 us; speedup 1.0000x reference)
//
#include <hip/hip_runtime.h>
#include <math.h>

#define B_ 512
#define T_ 128
#define D_ 512
#define O_ 10

// ---------------- GEMM1: h[(tc*B+b)*D + d] = b1[d] + sum_k (data[b][t][k]*drop[t][b][k]) * W1[d][k]
#define BM 128
#define BN 128
#define BK 16
#define LDSROW (BK + 4)   // pad to break bank-conflict strides

__global__ __launch_bounds__(256)
void gemm1_kernel(const float* __restrict__ data, const float* __restrict__ drop,
                  const float* __restrict__ W1, const float* __restrict__ b1,
                  float* __restrict__ hbuf, int t0)
{
    __shared__ float As[BM * LDSROW];
    __shared__ float Ws[BN * LDSROW];
    const int tid = threadIdx.x;
    const int R  = blockIdx.x * BM;     // chunk-row base (tc*512 + b_base)
    const int tc = R >> 9;              // chunk-local timestep (BM=128 divides B=512)
    const int b_base = R & 511;
    const int t  = t0 + tc;
    const int d0 = blockIdx.y * BN;

    const int tx = tid & 15;            // n-group (8 cols each)
    const int ty = tid >> 4;            // m-group (8 rows each)

    float acc[8][8];
#pragma unroll
    for (int i = 0; i < 8; ++i)
#pragma unroll
        for (int j = 0; j < 8; ++j) acc[i][j] = 0.f;

    const int lm0 = tid >> 2;           // 0..63
    const int lk0 = (tid & 3) * 4;      // 0,4,8,12
    const float* dataRow = data + ((size_t)b_base * T_ + t) * D_;  // + m*T_*D_ + k
    const float* dropRow = drop + ((size_t)t * B_ + b_base) * D_;  // + m*D_ + k
    const float* WRow    = W1 + (size_t)d0 * D_;                   // + m*D_ + k

    for (int k0 = 0; k0 < D_; k0 += BK) {
#pragma unroll
        for (int half = 0; half < 2; ++half) {
            const int m = lm0 + half * 64;
            const float4 dv = *(const float4*)(dataRow + (size_t)m * T_ * D_ + k0 + lk0);
            const float4 mv = *(const float4*)(dropRow + (size_t)m * D_ + k0 + lk0);
            float4 av;
            av.x = dv.x * mv.x; av.y = dv.y * mv.y;
            av.z = dv.z * mv.z; av.w = dv.w * mv.w;
            *(float4*)(&As[m * LDSROW + lk0]) = av;
            const float4 wv = *(const float4*)(WRow + (size_t)m * D_ + k0 + lk0);
            *(float4*)(&Ws[m * LDSROW + lk0]) = wv;
        }
        __syncthreads();
#pragma unroll
        for (int kk = 0; kk < BK; kk += 4) {
            float4 a[8], w[8];
#pragma unroll
            for (int i = 0; i < 8; ++i)
                a[i] = *(const float4*)(&As[(ty * 8 + i) * LDSROW + kk]);
#pragma unroll
            for (int j = 0; j < 8; ++j)
                w[j] = *(const float4*)(&Ws[(tx * 8 + j) * LDSROW + kk]);
#pragma unroll
            for (int i = 0; i < 8; ++i)
#pragma unroll
                for (int j = 0; j < 8; ++j) {
                    acc[i][j] = fmaf(a[i].x, w[j].x, acc[i][j]);
                    acc[i][j] = fmaf(a[i].y, w[j].y, acc[i][j]);
                    acc[i][j] = fmaf(a[i].z, w[j].z, acc[i][j]);
                    acc[i][j] = fmaf(a[i].w, w[j].w, acc[i][j]);
                }
        }
        __syncthreads();
    }

    // epilogue: add b1, store
#pragma unroll
    for (int i = 0; i < 8; ++i) {
        const int m = ty * 8 + i;
        float* op = hbuf + ((size_t)(R + m)) * D_ + d0 + tx * 8;
#pragma unroll
        for (int j = 0; j < 8; ++j)
            op[j] = acc[i][j] + b1[d0 + tx * 8 + j];
    }
}

// ---------------- BN stats -> per-(t,d) scale/shift (fp64 accumulate, deterministic)
__global__ __launch_bounds__(256)
void stats_kernel(const float* __restrict__ hbuf, const float* __restrict__ gamma,
                  const float* __restrict__ bn_beta,
                  float* __restrict__ scaleArr, float* __restrict__ shiftArr)
{
    const int tc = blockIdx.x;
    const int dt = blockIdx.y;                 // 64-wide d tile
    const int dl = threadIdx.x & 63;
    const int d  = dt * 64 + dl;
    const int brow = threadIdx.x >> 6;         // 0..3
    double s = 0.0, s2 = 0.0;
    const float* hp = hbuf + (size_t)tc * B_ * D_ + d;
    for (int b = brow; b < B_; b += 4) {
        const double v = (double)hp[(size_t)b * D_];
        s += v; s2 += v * v;
    }
    __shared__ double sh[2][4][64];
    sh[0][brow][dl] = s;
    sh[1][brow][dl] = s2;
    __syncthreads();
    if (threadIdx.x < 64) {
        const int dd = dt * 64 + threadIdx.x;
        const double S  = sh[0][0][threadIdx.x] + sh[0][1][threadIdx.x] +
                          sh[0][2][threadIdx.x] + sh[0][3][threadIdx.x];
        const double S2 = sh[1][0][threadIdx.x] + sh[1][1][threadIdx.x] +
                          sh[1][2][threadIdx.x] + sh[1][3][threadIdx.x];
        const double mean = S / (double)B_;
        const double var  = S2 / (double)B_ - mean * mean;
        const double rs   = 1.0 / sqrt(var + 1e-5);
        const double g    = (double)gamma[dd] * rs;
        scaleArr[tc * D_ + dd] = (float)g;
        shiftArr[tc * D_ + dd] = (float)((double)bn_beta[dd] - g * mean);
    }
}

// ---------------- Scan: per-batch-row recurrence, no grid syncs.
// grid = 512 blocks (one per b), 128 threads (4 features each).
__global__ __launch_bounds__(128)
void scan_kernel(const float* __restrict__ hbuf, const float* __restrict__ scaleArr,
                 const float* __restrict__ shiftArr, const float* __restrict__ W2,
                 const float* __restrict__ b2, float* __restrict__ out,
                 float* __restrict__ sMem1, float* __restrict__ sSpk1,
                 float* __restrict__ sMem2, float* __restrict__ sSpk2,
                 int t0, int Tc)
{
    const int b   = blockIdx.x;
    const int tid = threadIdx.x;
    const int d0  = tid * 4;
    const int wv  = tid >> 6;        // wave id (0..1)
    const int lane = tid & 63;

    float4 m1, s1;
    float mem2[O_], spk2[O_];
    if (t0 == 0) {
        m1 = make_float4(0.f, 0.f, 0.f, 0.f);
        s1 = make_float4(0.f, 0.f, 0.f, 0.f);
#pragma unroll
        for (int o = 0; o < O_; ++o) { mem2[o] = 0.f; spk2[o] = 0.f; }
    } else {
        m1 = *(const float4*)(sMem1 + (size_t)b * D_ + d0);
        s1 = *(const float4*)(sSpk1 + (size_t)b * D_ + d0);
#pragma unroll
        for (int o = 0; o < O_; ++o) { mem2[o] = sMem2[b * O_ + o]; spk2[o] = sSpk2[b * O_ + o]; }
    }

    float4 w2v[O_];
    float b2v[O_];
#pragma unroll
    for (int o = 0; o < O_; ++o) {
        w2v[o] = *(const float4*)(W2 + o * D_ + d0);
        b2v[o] = b2[o];
    }

    __shared__ float red[2][2][O_];   // [parity][wave][o]

    for (int tc = 0; tc < Tc; ++tc) {
        const int par = tc & 1;
        const float4 hv = *(const float4*)(hbuf + ((size_t)tc * B_ + b) * D_ + d0);
        const float4 sc = *(const float4*)(scaleArr + tc * D_ + d0);
        const float4 sf = *(const float4*)(shiftArr + tc * D_ + d0);

        float4 cur1;
        cur1.x = fmaf(sc.x, hv.x, sf.x);
        cur1.y = fmaf(sc.y, hv.y, sf.y);
        cur1.z = fmaf(sc.z, hv.z, sf.z);
        cur1.w = fmaf(sc.w, hv.w, sf.w);

        m1.x = fmaf(0.5f, m1.x, cur1.x) - s1.x;
        m1.y = fmaf(0.5f, m1.y, cur1.y) - s1.y;
        m1.z = fmaf(0.5f, m1.z, cur1.z) - s1.z;
        m1.w = fmaf(0.5f, m1.w, cur1.w) - s1.w;

        s1.x = ((m1.x - 1.0f) > 0.f) ? 1.f : 0.f;
        s1.y = ((m1.y - 1.0f) > 0.f) ? 1.f : 0.f;
        s1.z = ((m1.z - 1.0f) > 0.f) ? 1.f : 0.f;
        s1.w = ((m1.w - 1.0f) > 0.f) ? 1.f : 0.f;

        // GEMM2 partials + block reduce
        float p[O_];
#pragma unroll
        for (int o = 0; o < O_; ++o) {
            float v;
            v = s1.x * w2v[o].x;
            v = fmaf(s1.y, w2v[o].y, v);
            v = fmaf(s1.z, w2v[o].z, v);
            v = fmaf(s1.w, w2v[o].w, v);
            p[o] = v;
        }
#pragma unroll
        for (int o = 0; o < O_; ++o) {
#pragma unroll
            for (int off = 32; off > 0; off >>= 1)
                p[o] += __shfl_xor(p[o], off);
        }
        if (lane == 0) {
#pragma unroll
            for (int o = 0; o < O_; ++o) red[par][wv][o] = p[o];
        }
        __syncthreads();
#pragma unroll
        for (int o = 0; o < O_; ++o) {
            const float cur2 = red[par][0][o] + red[par][1][o] + b2v[o];
            mem2[o] = fmaf(0.5f, mem2[o], cur2) - spk2[o];
            spk2[o] = ((mem2[o] - 1.0f) > 0.f) ? 1.f : 0.f;
        }
        if (tid < O_)
            out[((size_t)(t0 + tc) * B_ + b) * O_ + tid] = spk2[tid];
    }

    // persist state for next chunk
    *(float4*)(sMem1 + (size_t)b * D_ + d0) = m1;
    *(float4*)(sSpk1 + (size_t)b * D_ + d0) = s1;
    if (tid < O_) {
        sMem2[b * O_ + tid] = mem2[tid];
        sSpk2[b * O_ + tid] = spk2[tid];
    }
}

extern "C" void kernel_launch(void* const* d_in, const int* in_sizes, int n_in,
                              void* d_out, int out_size, void* d_ws, size_t ws_size,
                              hipStream_t stream) {
    const float* data    = (const float*)d_in[0];
    const float* drop    = (const float*)d_in[1];
    const float* W1      = (const float*)d_in[2];
    const float* b1      = (const float*)d_in[3];
    const float* gamma   = (const float*)d_in[4];
    const float* bn_beta = (const float*)d_in[5];
    const float* W2      = (const float*)d_in[6];
    const float* b2      = (const float*)d_in[7];
    float* out = (float*)d_out;

    const size_t stateBytes = ((size_t)2 * B_ * D_ + (size_t)2 * B_ * O_) * 4;
    int Tc = T_;
    while (Tc > 1) {
        const size_t need = (size_t)Tc * B_ * D_ * 4 + (size_t)Tc * D_ * 8 + stateBytes;
        if (need <= ws_size) break;
        Tc >>= 1;
    }

    char* p = (char*)d_ws;
    float* hbuf     = (float*)p; p += (size_t)Tc * B_ * D_ * 4;
    float* scaleArr = (float*)p; p += (size_t)Tc * D_ * 4;
    float* shiftArr = (float*)p; p += (size_t)Tc * D_ * 4;
    float* sMem1    = (float*)p; p += (size_t)B_ * D_ * 4;
    float* sSpk1    = (float*)p; p += (size_t)B_ * D_ * 4;
    float* sMem2    = (float*)p; p += (size_t)B_ * O_ * 4;
    float* sSpk2    = (float*)p; p += (size_t)B_ * O_ * 4;

    for (int t0 = 0; t0 < T_; t0 += Tc) {
        dim3 g1((Tc * B_) / BM, D_ / BN);
        gemm1_kernel<<<g1, 256, 0, stream>>>(data, drop, W1, b1, hbuf, t0);
        stats_kernel<<<dim3(Tc, D_ / 64), 256, 0, stream>>>(hbuf, gamma, bn_beta, scaleArr, shiftArr);
        scan_kernel<<<B_, 128, 0, stream>>>(hbuf, scaleArr, shiftArr, W2, b2, out,
                                            sMem1, sSpk1, sMem2, sSpk2, t0, Tc);
    }
}